// Round 6
// baseline (710.984 us; speedup 1.0000x reference)
//
#include <hip/hip_runtime.h>
#include <cfloat>

// VQ-VAE vector quantizer. Round 6: single-barrier double-buffered BK=32
// pipeline — the vmcnt(0) barrier drain (was ~52% of argmin time) now overlaps
// compute. MFMA order identical to r5 (bit-identical scores).
// N=32768 rows, K=8192 codes, D=256.
#define K_CODES 8192
#define DIM     256
#define NROWS   32768

// d_out float offsets (outputs concatenated in reference return order)
#define O_ZQ    0
#define O_LOSS  8388608
#define O_IDX   8388609
#define O_NEMB  8421377
#define O_NCS   10518529
#define O_NEMAW 10526721

// ---- MFMA path params
#define NCH          2                    // code chunks
#define CODES_PER_CH (K_CODES / NCH)      // 4096
#define NT_TILES     (CODES_PER_CH / 256) // 16
#define KSTEPS       24                   // virtual K 768 / 32
#define NITER        (NT_TILES * KSTEPS)  // 384

typedef __attribute__((ext_vector_type(8))) short short8;
typedef __attribute__((ext_vector_type(4))) float floatx4;

__device__ __forceinline__ unsigned short f2bf_rne(float x) {
    unsigned u = __float_as_uint(x);
    u += 0x7fffu + ((u >> 16) & 1u);
    return (unsigned short)(u >> 16);
}
__device__ __forceinline__ float bf2f(unsigned short h) {
    return __uint_as_float(((unsigned)h) << 16);
}
__device__ __forceinline__ void async16(const void* g, void* l) {
    __builtin_amdgcn_global_load_lds(
        (const __attribute__((address_space(1))) void*)g,
        (__attribute__((address_space(3))) void*)l, 16, 0, 0);
}

// ---------------------------------------------------------------- fused convert: z & emb -> {hi,lo} bf16 + |e|^2 + zero
__global__ void k_prep(const float* __restrict__ z, const float* __restrict__ emb,
                       unsigned short* __restrict__ zcat, unsigned short* __restrict__ ecat,
                       float* __restrict__ esq, int* __restrict__ zero16k) {
    const int b = blockIdx.x;
    if (b < 8192) {
        const int i = b * 256 + threadIdx.x;         // float4 idx, 2,097,152
        const int row = i >> 6;
        const int col = (i & 63) << 2;
        float4 v = ((const float4*)z)[i];
        // fold -2 into z: bf16(-2z) == -2*bf16(z) exactly (pow2 scale)
        float nx = -2.0f * v.x, ny = -2.0f * v.y, nz = -2.0f * v.z, nw = -2.0f * v.w;
        ushort4 h, l;
        h.x = f2bf_rne(nx); l.x = f2bf_rne(nx - bf2f(h.x));
        h.y = f2bf_rne(ny); l.y = f2bf_rne(ny - bf2f(h.y));
        h.z = f2bf_rne(nz); l.z = f2bf_rne(nz - bf2f(h.z));
        h.w = f2bf_rne(nw); l.w = f2bf_rne(nw - bf2f(h.w));
        *(ushort4*)&zcat[(size_t)row * 512 + col]       = h;
        *(ushort4*)&zcat[(size_t)row * 512 + 256 + col] = l;
    } else {
        const int gid  = (b - 8192) * 256 + threadIdx.x;  // 0..524287
        if (gid < 2 * K_CODES) zero16k[gid] = 0;          // counts + cursor
        const int code = gid >> 6;
        const int lane = gid & 63;
        const int col  = lane << 2;
        float4 v = ((const float4*)emb)[code * 64 + lane];
        ushort4 h, l;
        h.x = f2bf_rne(v.x); l.x = f2bf_rne(v.x - bf2f(h.x));
        h.y = f2bf_rne(v.y); l.y = f2bf_rne(v.y - bf2f(h.y));
        h.z = f2bf_rne(v.z); l.z = f2bf_rne(v.z - bf2f(h.z));
        h.w = f2bf_rne(v.w); l.w = f2bf_rne(v.w - bf2f(h.w));
        *(ushort4*)&ecat[(size_t)code * 512 + col]       = h;
        *(ushort4*)&ecat[(size_t)code * 512 + 256 + col] = l;
        float s = fmaf(v.x, v.x, fmaf(v.y, v.y, fmaf(v.z, v.z, v.w * v.w)));
#pragma unroll
        for (int off = 32; off > 0; off >>= 1) s += __shfl_down(s, off, 64);
        if (lane == 0) esq[code] = s;
    }
}

// ---------------------------------------------------------------- MFMA argmin GEMM
// virtual K=768, BK=32, 128x256 block tile, double-buffered LDS, ONE barrier/iter.
// score(n,k) = esq[k] + dot(zcat_n, ecat_k segs), zcat encodes -2z.
// A segs {hi,hi,lo}: off_a=(k0&255)|((k0&512)>>1); B segs {hi,lo,hi}: off_b=k0&511.
// LDS swizzle (BK=32: row=64B=4x16B chunks): logical (row R, chunk C) stored at
// chunk position C ^ ((R>>1)&3). Staging lane L covers row L>>2, logical chunk
// (L&3)^((L>>3)&3); fragment b128 reads then hit 4 quads x 2 lanes in each row
// parity -> 2-way aliasing = free.
__global__ __launch_bounds__(256, 2) void k_argmin_mfma(
        const unsigned short* __restrict__ zcat, const unsigned short* __restrict__ ecat,
        const float* __restrict__ esq,
        float* __restrict__ part_v, int* __restrict__ part_i) {
    __shared__ __align__(16) unsigned short a_s[2][128 * 32];  // 2 x 8 KB
    __shared__ __align__(16) unsigned short b_s[2][256 * 32];  // 2 x 16 KB (48 KB total)
    const int t    = threadIdx.x;
    const int w    = t >> 6;
    const int lane = t & 63;
    const int quad = lane >> 4;
    const int m    = lane & 15;
    const int wrow = (w >> 1) * 64;
    const int wcol = (w & 1) * 128;
    const int row0   = blockIdx.x * 128;
    const int cbase0 = blockIdx.y * CODES_PER_CH;
    // staging geometry: chunk = 16 rows x 32 ushort; lane L -> row L>>2, 16B slot L&3
    const int srow = lane >> 2;
    const int sC   = (lane & 3) ^ ((lane >> 3) & 3);   // logical chunk this lane fetches
    const size_t aBase = (size_t)(row0 + srow) * 512 + sC * 8;
    const size_t bBase = (size_t)(cbase0 + srow) * 512 + sC * 8;
    // fragment-read swizzle (iteration-invariant): slot = quad ^ ((m>>1)&3)
    const int xo = (quad ^ ((m >> 1) & 3)) * 8;

    float    best_v[16];
    unsigned best_p[4];     // per i: 4 reg-slots x 8-bit candidate (nt*8+j)
#pragma unroll
    for (int r = 0; r < 16; ++r) best_v[r] = FLT_MAX;
#pragma unroll
    for (int i = 0; i < 4; ++i) best_p[i] = 0u;

    // stage iteration (nt_, kk_) into buffer `buf`: 24 chunks over 4 waves
    auto stage = [&](int nt_, int kk_, int buf) {
        const int k0    = kk_ * 32;
        const int off_a = (k0 & 255) | ((k0 & 512) >> 1);
        const int off_b = k0 & 511;
#pragma unroll
        for (int c = 0; c < 6; ++c) {
            const int u = w * 6 + c;
            if (u < 8) {
                async16(zcat + aBase + (size_t)u * (16 * 512) + off_a,
                        &a_s[buf][u * 512]);
            } else {
                const int q = u - 8;
                async16(ecat + bBase + (size_t)(nt_ * 256 + q * 16) * 512 + off_b,
                        &b_s[buf][q * 512]);
            }
        }
    };

    floatx4 acc[4][8];
#pragma unroll
    for (int j = 0; j < 8; ++j) {
        const float es = esq[cbase0 + wcol + j * 16 + m];
#pragma unroll
        for (int i = 0; i < 4; ++i) acc[i][j] = (floatx4){es, es, es, es};
    }

    stage(0, 0, 0);
    __syncthreads();               // drain prologue loads

    int kk = 0, nt = 0;
    for (int it = 0; it < NITER; ++it) {
        int kk1 = kk + 1, nt1 = nt;
        if (kk1 == KSTEPS) { kk1 = 0; nt1 = nt + 1; }
        const int cur = it & 1;
        // 1) fragment reads from current buffer (BEFORE staging, so no
        //    compiler vmcnt-wait can land between stage-issue and mfma)
        short8 af[4], bfr[8];
        const unsigned short* ap = a_s[cur];
        const unsigned short* bp = b_s[cur];
#pragma unroll
        for (int i = 0; i < 4; ++i)
            af[i] = *(const short8*)&ap[(wrow + i * 16 + m) * 32 + xo];
#pragma unroll
        for (int j = 0; j < 8; ++j)
            bfr[j] = *(const short8*)&bp[(wcol + j * 16 + m) * 32 + xo];
        // 2) issue async staging for next iteration into the other buffer
        if (it + 1 < NITER) stage(nt1, kk1, cur ^ 1);
        // 3) MFMAs
#pragma unroll
        for (int i = 0; i < 4; ++i)
#pragma unroll
            for (int j = 0; j < 8; ++j)
                acc[i][j] = __builtin_amdgcn_mfma_f32_16x16x32_bf16(
                    af[i], bfr[j], acc[i][j], 0, 0, 0);
        // 4) per-nt epilogue: acc IS the score; codes ascend in (nt,j) ->
        //    strict < keeps first-min
        if (kk == KSTEPS - 1) {
#pragma unroll
            for (int j = 0; j < 8; ++j) {
                const unsigned cand = (unsigned)(nt * 8 + j);   // 7 bits
#pragma unroll
                for (int i = 0; i < 4; ++i)
#pragma unroll
                    for (int reg = 0; reg < 4; ++reg) {
                        const float s = acc[i][j][reg];
                        const int r = i * 4 + reg;
                        if (s < best_v[r]) {
                            best_v[r] = s;
                            best_p[i] = (best_p[i] & ~(255u << (reg * 8)))
                                        | (cand << (reg * 8));
                        }
                    }
            }
            if (nt1 < NT_TILES) {
                const int cbn = cbase0 + nt1 * 256;
#pragma unroll
                for (int j = 0; j < 8; ++j) {
                    const float es = esq[cbn + wcol + j * 16 + m];
#pragma unroll
                    for (int i = 0; i < 4; ++i) acc[i][j] = (floatx4){es, es, es, es};
                }
            }
        }
        __syncthreads();           // single barrier: drains next-iter loads
        kk = kk1; nt = nt1;
    }

    // reconstruct codes, butterfly across the 16 lanes sharing each row
    float* redv = (float*)a_s;     // [128][2]
    int*   redi = (int*)b_s;       // [128][2]
#pragma unroll
    for (int i = 0; i < 4; ++i)
#pragma unroll
        for (int reg = 0; reg < 4; ++reg) {
            const int r = i * 4 + reg;
            const unsigned b = (best_p[i] >> (reg * 8)) & 255u;
            float v  = best_v[r];
            int   bi = cbase0 + (int)(b >> 3) * 256 + wcol + (int)(b & 7) * 16 + m;
#pragma unroll
            for (int off = 1; off < 16; off <<= 1) {
                const float ov = __shfl_xor(v, off, 64);
                const int   oi = __shfl_xor(bi, off, 64);
                if (ov < v || (ov == v && oi < bi)) { v = ov; bi = oi; }
            }
            if (m == 0) {
                const int row = wrow + i * 16 + quad * 4 + reg;
                redv[row * 2 + (w & 1)] = v;
                redi[row * 2 + (w & 1)] = bi;
            }
        }
    __syncthreads();
    if (t < 128) {
        const float v0 = redv[t * 2], v1 = redv[t * 2 + 1];
        const int   i0 = redi[t * 2], i1 = redi[t * 2 + 1];
        const bool  b1 = (v1 < v0) || (v1 == v0 && i1 < i0);
        const size_t o = (size_t)blockIdx.y * NROWS + blockIdx.x * 128 + t;
        part_v[o] = b1 ? v1 : v0;
        part_i[o] = b1 ? i1 : i0;
    }
}

// ---------------------------------------------------------------- merge partials + histogram
__global__ void k_reduce_part(const float* __restrict__ pv, const int* __restrict__ pi,
                              int* __restrict__ idx_i, float* __restrict__ idx_f,
                              int* __restrict__ counts) {
    const int r = blockIdx.x * blockDim.x + threadIdx.x;
    float v = pv[r]; int bi = pi[r];
#pragma unroll
    for (int c = 1; c < NCH; ++c) {
        const float v2 = pv[(size_t)c * NROWS + r];
        const int   i2 = pi[(size_t)c * NROWS + r];
        if (v2 < v || (v2 == v && i2 < bi)) { v = v2; bi = i2; }
    }
    idx_i[r] = bi;
    idx_f[r] = (float)bi;
    atomicAdd(&counts[bi], 1);
}

// ---------------------------------------------------------------- scan + new_cluster_size + n  (1 block, 1024 thr)
__global__ void k_scan_ncs(const int* __restrict__ counts, const float* __restrict__ ema_cs,
                           int* __restrict__ offsets, float* __restrict__ ncs_out,
                           float* __restrict__ ntot) {
    __shared__ int   wsum[16];
    __shared__ float red[16];
    const int t = threadIdx.x;
    const int lane = t & 63, w = t >> 6;
    int c[8]; int s = 0; float fs = 0.0f;
#pragma unroll
    for (int u = 0; u < 8; ++u) {
        c[u] = counts[t * 8 + u]; s += c[u];
        const float v = fmaf(0.99f, ema_cs[t * 8 + u], 0.01f * (float)c[u]);
        ncs_out[t * 8 + u] = v;
        fs += v;
    }
    int inc = s;
#pragma unroll
    for (int off = 1; off < 64; off <<= 1) {
        const int n = __shfl_up(inc, off, 64);
        if (lane >= off) inc += n;
    }
#pragma unroll
    for (int off = 32; off > 0; off >>= 1) fs += __shfl_down(fs, off, 64);
    if (lane == 63) wsum[w] = inc;
    if (lane == 0)  red[w]  = fs;
    __syncthreads();
    if (t < 16) {
        int v = wsum[t];
#pragma unroll
        for (int off = 1; off < 16; off <<= 1) {
            const int n = __shfl_up(v, off, 64);
            if (t >= off) v += n;
        }
        wsum[t] = v;
        float fv = red[t];
#pragma unroll
        for (int off = 8; off > 0; off >>= 1) fv += __shfl_down(fv, off, 16);
        if (t == 0) *ntot = fv;
    }
    __syncthreads();
    int base = (w > 0 ? wsum[w - 1] : 0) + (inc - s);
#pragma unroll
    for (int u = 0; u < 8; ++u) { offsets[t * 8 + u] = base; base += c[u]; }
}

// ---------------------------------------------------------------- zq + loss partials + bucket scatter
__global__ void k_zq(const float* __restrict__ z, const float* __restrict__ emb,
                     const int* __restrict__ idx_i, const int* __restrict__ offsets,
                     int* __restrict__ cursor, int* __restrict__ buckets,
                     float* __restrict__ zq, float* __restrict__ losspart) {
    __shared__ float lred[4];
    const int t = threadIdx.x;
    const int wr = t >> 6, lane = t & 63;
    const int row = blockIdx.x * 4 + wr;
    const int code = idx_i[row];
    float4 zv = ((const float4*)z)[row * 64 + lane];
    float4 ev = ((const float4*)emb)[(size_t)code * 64 + lane];
    float4 o = make_float4(zv.x + (ev.x - zv.x), zv.y + (ev.y - zv.y),
                           zv.z + (ev.z - zv.z), zv.w + (ev.w - zv.w));
    ((float4*)zq)[row * 64 + lane] = o;
    float dx = ev.x - zv.x, dy = ev.y - zv.y, dz = ev.z - zv.z, dw = ev.w - zv.w;
    float s = fmaf(dx, dx, fmaf(dy, dy, fmaf(dz, dz, dw * dw)));
#pragma unroll
    for (int off = 32; off > 0; off >>= 1) s += __shfl_down(s, off, 64);
    if (lane == 0) {
        lred[wr] = s;
        const int pos = atomicAdd(&cursor[code], 1);
        buckets[offsets[code] + pos] = row;
    }
    __syncthreads();
    if (t == 0) losspart[blockIdx.x] = (lred[0] + lred[1]) + (lred[2] + lred[3]);
}

// ---------------------------------------------------------------- dw + new_ema_w + new_embedding (+loss tail block)
__global__ void k_dw_nemb(const float* __restrict__ z, const float* __restrict__ ema_w,
                          const int* __restrict__ counts, const int* __restrict__ offsets,
                          const int* __restrict__ buckets, const float* __restrict__ ncs,
                          const float* __restrict__ ntot_p, const float* __restrict__ losspart,
                          float* __restrict__ nemaw, float* __restrict__ nemb,
                          float* __restrict__ loss_out) {
    __shared__ float lred[4];
    if (blockIdx.x == K_CODES) {          // loss finalize
        const int t = threadIdx.x;        // 256
        float s = 0.0f;
        for (int i = t; i < 8192; i += 256) s += losspart[i];
#pragma unroll
        for (int off = 32; off > 0; off >>= 1) s += __shfl_down(s, off, 64);
        if ((t & 63) == 0) lred[t >> 6] = s;
        __syncthreads();
        if (t == 0)
            *loss_out = 0.25f * ((lred[0] + lred[1]) + (lred[2] + lred[3])) / 8388608.0f;
        return;
    }
    const int code = blockIdx.x;
    const int d    = threadIdx.x;         // 256 = DIM
    const int cnt  = counts[code];
    const int off  = offsets[code];
    float acc = 0.0f;
    for (int it = 0; it < cnt; ++it)
        acc += z[(size_t)buckets[off + it] * DIM + d];
    const float wv = fmaf(0.99f, ema_w[(size_t)code * DIM + d], 0.01f * acc);
    nemaw[(size_t)code * DIM + d] = wv;
    const float n  = *ntot_p;
    const float cs = (ncs[code] + 1e-5f) * (n / (n + (float)K_CODES * 1e-5f));
    nemb[(size_t)code * DIM + d] = wv / cs;
}

// ================================================================ fp32 fallback path (round-1 verified)
#define BM   64
#define BN   128
#define LSTR 36

__global__ void k_esq_zero_fb(const float* __restrict__ emb, float* __restrict__ esq,
                              float* __restrict__ zbuf) {
    const int gid  = blockIdx.x * blockDim.x + threadIdx.x;
    if (gid < K_CODES + 2) zbuf[gid] = 0.0f;
    const int code = gid >> 6;
    const int lane = gid & 63;
    float4 v = ((const float4*)emb)[code * 64 + lane];
    float s = fmaf(v.x, v.x, fmaf(v.y, v.y, fmaf(v.z, v.z, v.w * v.w)));
#pragma unroll
    for (int off = 32; off > 0; off >>= 1) s += __shfl_down(s, off, 64);
    if (lane == 0) esq[code] = s;
}

__global__ void k_init_nemaw_fb(const float* __restrict__ ema_w, float* __restrict__ out) {
    const int i = blockIdx.x * blockDim.x + threadIdx.x;
    float4 v = ((const float4*)ema_w)[i];
    ((float4*)out)[i] = make_float4(0.99f * v.x, 0.99f * v.y, 0.99f * v.z, 0.99f * v.w);
}

__global__ __launch_bounds__(256, 2) void k_argmin_fb(
        const float* __restrict__ z, const float* __restrict__ emb,
        const float* __restrict__ esq, int* __restrict__ idx_i, float* __restrict__ idx_f) {
    __shared__ float z_s[BM * LSTR];
    __shared__ float e_s[BN * LSTR];
    const int t = threadIdx.x, tx = t & 15, ty = t >> 4;
    const int row0 = blockIdx.x * BM;
    float best[4]; int bidx[4];
#pragma unroll
    for (int r = 0; r < 4; ++r) { best[r] = FLT_MAX; bidx[r] = 0; }
    for (int k0 = 0; k0 < K_CODES; k0 += BN) {
        float acc[4][8];
#pragma unroll
        for (int r = 0; r < 4; ++r)
#pragma unroll
            for (int c = 0; c < 8; ++c) acc[r][c] = 0.0f;
        for (int d0 = 0; d0 < DIM; d0 += 32) {
            __syncthreads();
#pragma unroll
            for (int i = 0; i < 2; ++i) {
                int f = i * 256 + t, r = f >> 3, c4 = (f & 7) << 2;
                *(float4*)&z_s[r * LSTR + c4] =
                    *(const float4*)(z + (size_t)(row0 + r) * DIM + d0 + c4);
            }
#pragma unroll
            for (int i = 0; i < 4; ++i) {
                int f = i * 256 + t, c = f >> 3, c4 = (f & 7) << 2;
                *(float4*)&e_s[c * LSTR + c4] =
                    *(const float4*)(emb + (size_t)(k0 + c) * DIM + d0 + c4);
            }
            __syncthreads();
#pragma unroll
            for (int dd = 0; dd < 32; dd += 4) {
                float4 a[4], b[8];
#pragma unroll
                for (int j = 0; j < 4; ++j)
                    a[j] = *(const float4*)&z_s[(ty * 4 + j) * LSTR + dd];
#pragma unroll
                for (int j = 0; j < 8; ++j)
                    b[j] = *(const float4*)&e_s[(tx + 16 * j) * LSTR + dd];
#pragma unroll
                for (int r = 0; r < 4; ++r)
#pragma unroll
                    for (int c = 0; c < 8; ++c) {
                        acc[r][c] = fmaf(a[r].x, b[c].x, acc[r][c]);
                        acc[r][c] = fmaf(a[r].y, b[c].y, acc[r][c]);
                        acc[r][c] = fmaf(a[r].z, b[c].z, acc[r][c]);
                        acc[r][c] = fmaf(a[r].w, b[c].w, acc[r][c]);
                    }
            }
        }
#pragma unroll
        for (int c = 0; c < 8; ++c) {
            const int code = k0 + tx + 16 * c;
            const float es = esq[code];
#pragma unroll
            for (int r = 0; r < 4; ++r) {
                float s = fmaf(-2.0f, acc[r][c], es);
                if (s < best[r] || (s == best[r] && code < bidx[r])) {
                    best[r] = s; bidx[r] = code;
                }
            }
        }
    }
    __syncthreads();
    float* rv = e_s; int* ri = (int*)z_s;
#pragma unroll
    for (int r = 0; r < 4; ++r) {
        rv[(ty * 4 + r) * 16 + tx] = best[r];
        ri[(ty * 4 + r) * 16 + tx] = bidx[r];
    }
    __syncthreads();
    if (t < 64) {
        float mv = rv[t * 16]; int mi = ri[t * 16];
#pragma unroll
        for (int i = 1; i < 16; ++i) {
            float v = rv[t * 16 + i]; int vi = ri[t * 16 + i];
            if (v < mv || (v == mv && vi < mi)) { mv = v; mi = vi; }
        }
        idx_i[row0 + t] = mi;
        idx_f[row0 + t] = (float)mi;
    }
}

__global__ void k_gather_fb(const float* __restrict__ z, const float* __restrict__ emb,
                            const int* __restrict__ idx_i, float* __restrict__ zq,
                            float* __restrict__ nemaw, float* __restrict__ counts,
                            float* __restrict__ loss) {
    const int gid  = blockIdx.x * blockDim.x + threadIdx.x;
    const int row  = gid >> 6;
    const int lane = gid & 63;
    const int code = idx_i[row];
    float4 zv = ((const float4*)z)[row * 64 + lane];
    float4 ev = ((const float4*)emb)[(size_t)code * 64 + lane];
    float4 o = make_float4(zv.x + (ev.x - zv.x), zv.y + (ev.y - zv.y),
                           zv.z + (ev.z - zv.z), zv.w + (ev.w - zv.w));
    ((float4*)zq)[row * 64 + lane] = o;
    float dx = ev.x - zv.x, dy = ev.y - zv.y, dz = ev.z - zv.z, dw = ev.w - zv.w;
    float s = fmaf(dx, dx, fmaf(dy, dy, fmaf(dz, dz, dw * dw)));
#pragma unroll
    for (int off = 32; off > 0; off >>= 1) s += __shfl_down(s, off, 64);
    if (lane == 0) { atomicAdd(loss, s); atomicAdd(&counts[code], 1.0f); }
    float* base = nemaw + (size_t)code * DIM + lane * 4;
    atomicAdd(base + 0, 0.01f * zv.x);
    atomicAdd(base + 1, 0.01f * zv.y);
    atomicAdd(base + 2, 0.01f * zv.z);
    atomicAdd(base + 3, 0.01f * zv.w);
}

__global__ void k_ncs_fb(const float* __restrict__ ema_cs, const float* __restrict__ counts,
                         float* __restrict__ ncs_out, float* __restrict__ ntot,
                         const float* __restrict__ loss_in, float* __restrict__ loss_out) {
    __shared__ float red[16];
    const int t = threadIdx.x;
    float s = 0.0f;
    for (int i = t; i < K_CODES; i += 1024) {
        float v = fmaf(0.99f, ema_cs[i], 0.01f * counts[i]);
        ncs_out[i] = v; s += v;
    }
#pragma unroll
    for (int off = 32; off > 0; off >>= 1) s += __shfl_down(s, off, 64);
    if ((t & 63) == 0) red[t >> 6] = s;
    __syncthreads();
    if (t < 16) {
        float v = red[t];
#pragma unroll
        for (int off = 8; off > 0; off >>= 1) v += __shfl_down(v, off, 16);
        if (t == 0) { *ntot = v; *loss_out = 0.25f * (*loss_in) / 8388608.0f; }
    }
}

__global__ void k_nemb_fb(const float* __restrict__ nemaw, const float* __restrict__ ncs,
                          const float* __restrict__ ntot_p, float* __restrict__ nemb) {
    const int i4 = blockIdx.x * blockDim.x + threadIdx.x;
    const int k  = i4 >> 6;
    const float n   = *ntot_p;
    const float inv = n / (n + (float)K_CODES * 1e-5f);
    const float cs  = (ncs[k] + 1e-5f) * inv;
    float4 wv = ((const float4*)nemaw)[i4];
    ((float4*)nemb)[i4] = make_float4(wv.x / cs, wv.y / cs, wv.z / cs, wv.w / cs);
}

extern "C" void kernel_launch(void* const* d_in, const int* in_sizes, int n_in,
                              void* d_out, int out_size, void* d_ws, size_t ws_size,
                              hipStream_t stream) {
    const float* z      = (const float*)d_in[0];
    const float* emb    = (const float*)d_in[1];
    const float* ema_cs = (const float*)d_in[2];
    const float* ema_w  = (const float*)d_in[3];
    float* out = (float*)d_out;
    char* wsb = (char*)d_ws;

    // ---- MFMA-path workspace layout (bytes), total 43,417,616
    unsigned short* zcat    = (unsigned short*)wsb;                  // 33,554,432
    unsigned short* ecat    = (unsigned short*)(wsb + 33554432);     //  8,388,608
    float*          part_v  = (float*)(wsb + 41943040);              //    524,288
    int*            part_i  = (int*)  (wsb + 42467328);              //    524,288
    float*          esq     = (float*)(wsb + 42991616);              //     32,768
    int*            ws_idx  = (int*)  (wsb + 43024384);              //    131,072
    int*            counts  = (int*)  (wsb + 43155456);              //     32,768
    int*            cursor  = (int*)  (wsb + 43188224);              //     32,768 (contiguous w/ counts)
    int*            offsets = (int*)  (wsb + 43220992);              //     32,768
    int*            buckets = (int*)  (wsb + 43253760);              //    131,072
    float*          lpart   = (float*)(wsb + 43384832);              //     32,768
    float*          ws_loss = (float*)(wsb + 43417600);
    float*          ws_ntot = ws_loss + 1;

    if (ws_size >= (size_t)43417616) {
        k_prep       <<<10240, 256, 0, stream>>>(z, emb, zcat, ecat, esq, counts);
        k_argmin_mfma<<<dim3(NROWS / 128, NCH), 256, 0, stream>>>(
            zcat, ecat, esq, part_v, part_i);
        k_reduce_part<<<NROWS / 256, 256, 0, stream>>>(part_v, part_i, ws_idx,
                                                       out + O_IDX, counts);
        k_scan_ncs   <<<1, 1024, 0, stream>>>(counts, ema_cs, offsets,
                                              out + O_NCS, ws_ntot);
        k_zq         <<<NROWS / 4, 256, 0, stream>>>(z, emb, ws_idx, offsets, cursor,
                                                     buckets, out + O_ZQ, lpart);
        k_dw_nemb    <<<K_CODES + 1, 256, 0, stream>>>(z, ema_w, counts, offsets, buckets,
                                                       out + O_NCS, ws_ntot, lpart,
                                                       out + O_NEMAW, out + O_NEMB,
                                                       out + O_LOSS);
    } else {
        // small-ws fallback (round-1 verified fp32 path)
        int*   f_idx    = (int*)wsb;
        float* f_counts = (float*)(wsb + 131072);
        float* f_loss   = f_counts + K_CODES;
        float* f_ntot   = f_loss + 1;
        float* f_esq    = (float*)(wsb + 163856);
        k_esq_zero_fb  <<<2048, 256, 0, stream>>>(emb, f_esq, f_counts);
        k_init_nemaw_fb<<<2048, 256, 0, stream>>>(ema_w, out + O_NEMAW);
        k_argmin_fb    <<<NROWS / BM, 256, 0, stream>>>(z, emb, f_esq, f_idx, out + O_IDX);
        k_gather_fb    <<<NROWS / 4, 256, 0, stream>>>(z, emb, f_idx, out + O_ZQ,
                                                       out + O_NEMAW, f_counts, f_loss);
        k_ncs_fb       <<<1, 1024, 0, stream>>>(ema_cs, f_counts, out + O_NCS, f_ntot,
                                                f_loss, out + O_LOSS);
        k_nemb_fb      <<<2048, 256, 0, stream>>>(out + O_NEMAW, out + O_NCS, f_ntot,
                                                  out + O_NEMB);
    }
}